// Round 8
// baseline (325.825 us; speedup 1.0000x reference)
//
#include <hip/hip_runtime.h>
#include <hip/hip_fp16.h>
#include <math.h>

#define N_NODES 100000
#define N_RELS  3
#define N_EDGES 400000
#define D       128
#define NTOT    (N_RELS * N_NODES)   // 300000
#define ELL_W   12
#define OVF_CAP 4096
#define BSH     9                    // bucket = node >> 9 (512 nodes/bucket)
#define NB      196                  // ceil(100000/512)
#define BCAP    3072                 // per (rel,bucket) segment capacity
#define CHUNK   4096                 // edges per pass1 block
#define NCH     98                   // ceil(400000/4096)
#define PASS1_BLKS (NCH * N_RELS)    // 294
#define GEMM_BLKS  782               // ceil(100000/128)

typedef _Float16 f16x8 __attribute__((ext_vector_type(8)));
typedef float    f32x4 __attribute__((ext_vector_type(4)));

// W transpose + fp16 convert: Wt[r][j][k] = fp16(W[r][k][j]); bsum[j] = mean_r b[r][j]
__global__ void prep_w_kernel(const float* __restrict__ W, const float* __restrict__ b,
                              ushort* __restrict__ Wt, float* __restrict__ bsum) {
    int id = blockIdx.x * 256 + threadIdx.x;
    if (id < 3 * D * D) {
        int r = id >> 14;
        int rem = id & 16383;
        int k = rem >> 7, j = rem & 127;
        Wt[r * 16384 + j * 128 + k] = __builtin_bit_cast(ushort, (_Float16)W[id]);
    }
    if (blockIdx.x == 0 && threadIdx.x < D) {
        int j = threadIdx.x;
        bsum[j] = (b[j] + b[D + j] + b[2 * D + j]) * (1.0f / 3.0f);
    }
}

// Fused: GEMM blocks compute h = fp16(x @ W_rel); pass1 blocks bucket-partition
// edges (dst-partition as (s,t) pairs, src-partition as s) with one global
// atomic per (block,bucket) segment reservation.
__global__ __launch_bounds__(256) void fused_kernel(
    const float* __restrict__ x, const ushort* __restrict__ Wt,
    const int* __restrict__ edges, ushort* __restrict__ h,
    int2* __restrict__ part_dst, int* __restrict__ part_src,
    int* __restrict__ gcur_dst, int* __restrict__ gcur_src) {
    __shared__ union {
        ushort Bt[128 * 128];                       // 32 KB (gemm role)
        struct { int s[CHUNK]; int t[CHUNK]; } st;  // 32 KB (pass1 role)
    } U;
    __shared__ int histd[NB], hists[NB], segd[NB], segs[NB];

    const int bid = blockIdx.x;
    const int tid = threadIdx.x;
    bool is_fill;
    int gid;
    if (bid < 2 * PASS1_BLKS) { is_fill = (bid & 1); gid = bid >> 1; }
    else                      { is_fill = false;     gid = bid - PASS1_BLKS; }

    if (!is_fill) {
        const int n0 = gid * 128;
        const int w = tid >> 6, l = tid & 63;
        const int wrow = w * 32;
        const int lr = l & 15, lk = (l >> 4) * 8;

        f16x8 a[2][4];
        #pragma unroll
        for (int fi = 0; fi < 2; ++fi) {
            int row = n0 + wrow + fi * 16 + lr;
            row = min(row, N_NODES - 1);
            const float* xp = x + (size_t)row * 128 + lk;
            #pragma unroll
            for (int ks = 0; ks < 4; ++ks) {
                float4 va = *(const float4*)(xp + ks * 32);
                float4 vb = *(const float4*)(xp + ks * 32 + 4);
                f16x8 t;
                t[0] = (_Float16)va.x; t[1] = (_Float16)va.y;
                t[2] = (_Float16)va.z; t[3] = (_Float16)va.w;
                t[4] = (_Float16)vb.x; t[5] = (_Float16)vb.y;
                t[6] = (_Float16)vb.z; t[7] = (_Float16)vb.w;
                a[fi][ks] = t;
            }
        }

        for (int rel = 0; rel < 3; ++rel) {
            __syncthreads();
            {
                const ushort* Wg = Wt + rel * 16384;
                #pragma unroll
                for (int c = 0; c < 8; ++c) {
                    int id = c * 256 + tid;
                    int j = id >> 4, k8 = id & 15;
                    uint4 v = *(const uint4*)(Wg + j * 128 + k8 * 8);
                    int ba = (j * 256 + k8 * 16) ^ ((j & 7) << 4);
                    *(uint4*)((char*)U.Bt + ba) = v;
                }
            }
            __syncthreads();

            f32x4 acc[2][8];
            #pragma unroll
            for (int fi = 0; fi < 2; ++fi)
                #pragma unroll
                for (int fj = 0; fj < 8; ++fj)
                    acc[fi][fj] = (f32x4){0.f, 0.f, 0.f, 0.f};

            #pragma unroll
            for (int ks = 0; ks < 4; ++ks) {
                f16x8 bfr[8];
                #pragma unroll
                for (int fj = 0; fj < 8; ++fj) {
                    int j = fj * 16 + lr;
                    int ba = (j * 256 + (ks * 32 + lk) * 2) ^ ((j & 7) << 4);
                    bfr[fj] = *(f16x8*)((char*)U.Bt + ba);
                }
                #pragma unroll
                for (int fi = 0; fi < 2; ++fi)
                    #pragma unroll
                    for (int fj = 0; fj < 8; ++fj)
                        acc[fi][fj] = __builtin_amdgcn_mfma_f32_16x16x32_f16(
                            a[fi][ks], bfr[fj], acc[fi][fj], 0, 0, 0);
            }

            const int cr4 = (l >> 4) * 4;
            #pragma unroll
            for (int fi = 0; fi < 2; ++fi) {
                int rbase = n0 + wrow + fi * 16 + cr4;
                #pragma unroll
                for (int fj = 0; fj < 8; ++fj) {
                    int col = fj * 16 + lr;
                    #pragma unroll
                    for (int i = 0; i < 4; ++i) {
                        int row = rbase + i;
                        if (row < N_NODES)
                            h[(size_t)row * 384 + rel * 128 + col] =
                                __builtin_bit_cast(ushort, (_Float16)acc[fi][fj][i]);
                    }
                }
            }
        }
    } else {
        const int rel   = gid / NCH;
        const int chunk = gid - rel * NCH;
        const int e0 = chunk * CHUNK;
        const int ne = min(CHUNK, N_EDGES - e0);
        const int* src = edges + (size_t)(rel * 2 + 0) * N_EDGES;
        const int* dst = edges + (size_t)(rel * 2 + 1) * N_EDGES;

        for (int i = tid; i < NB; i += 256) { histd[i] = 0; hists[i] = 0; }
        __syncthreads();
        for (int i = tid; i < ne; i += 256) {
            int s = src[e0 + i], t = dst[e0 + i];
            U.st.s[i] = s; U.st.t[i] = t;
            atomicAdd(&histd[t >> BSH], 1);
            atomicAdd(&hists[s >> BSH], 1);
        }
        __syncthreads();
        for (int i = tid; i < NB; i += 256) {
            int hd = histd[i];
            segd[i] = hd ? atomicAdd(&gcur_dst[rel * NB + i], hd) : 0;
            int hs = hists[i];
            segs[i] = hs ? atomicAdd(&gcur_src[rel * NB + i], hs) : 0;
            histd[i] = 0; hists[i] = 0;   // reuse as local cursors
        }
        __syncthreads();
        for (int i = tid; i < ne; i += 256) {
            int s = U.st.s[i], t = U.st.t[i];
            int bd = t >> BSH;
            int p = segd[bd] + atomicAdd(&histd[bd], 1);
            if (p < BCAP) part_dst[(size_t)(rel * NB + bd) * BCAP + p] = make_int2(s, t);
            int bs = s >> BSH;
            int q = segs[bs] + atomicAdd(&hists[bs], 1);
            if (q < BCAP) part_src[(size_t)(rel * NB + bs) * BCAP + q] = s;
        }
    }
}

// Per (bucket, rel): build 12-wide ELL + deg/rsqrt tables in LDS, write dense.
__global__ __launch_bounds__(256) void pass2_kernel(
    const int2* __restrict__ part_dst, const int* __restrict__ part_src,
    const int* __restrict__ gcur_dst, const int* __restrict__ gcur_src,
    int* __restrict__ ell, int* __restrict__ deg_in,
    float* __restrict__ rdi, float* __restrict__ rdo,
    int* __restrict__ ovf_cnt, int2* __restrict__ ovf) {
    __shared__ int cnt[512];
    __shared__ int lell[512 * ELL_W];   // 24 KB
    const int b = blockIdx.x, rel = blockIdx.y;
    const int tid = threadIdx.x;
    const int n0 = b << BSH;
    const int nvalid = min(512, N_NODES - n0);

    for (int i = tid; i < 512; i += 256) cnt[i] = 0;
    __syncthreads();
    const int m = min(gcur_dst[rel * NB + b], BCAP);
    const int2* pp = part_dst + (size_t)(rel * NB + b) * BCAP;
    for (int i = tid; i < m; i += 256) {
        int2 e = pp[i];
        int li = e.y - n0;
        int p = atomicAdd(&cnt[li], 1);
        if (p < ELL_W) lell[li * ELL_W + p] = e.x;
        else {
            int o = atomicAdd(ovf_cnt, 1);
            if (o < OVF_CAP) ovf[o] = make_int2(e.x, e.y | (rel << 20));
        }
    }
    __syncthreads();
    for (int i = tid; i < nvalid; i += 256) {
        int c = cnt[i];
        deg_in[rel * N_NODES + n0 + i] = c;
        rdi[rel * N_NODES + n0 + i] = rsqrtf((float)max(c, 1));
    }
    for (int i = tid; i < nvalid * ELL_W; i += 256)
        ell[(size_t)(rel * N_NODES + n0) * ELL_W + i] = lell[i];
    __syncthreads();
    for (int i = tid; i < 512; i += 256) cnt[i] = 0;
    __syncthreads();
    const int m2 = min(gcur_src[rel * NB + b], BCAP);
    const int* ps = part_src + (size_t)(rel * NB + b) * BCAP;
    for (int i = tid; i < m2; i += 256) atomicAdd(&cnt[ps[i] - n0], 1);
    __syncthreads();
    for (int i = tid; i < nvalid; i += 256)
        rdo[rel * N_NODES + n0 + i] = rsqrtf((float)max(cnt[i], 1));
}

// out[n,:] = (1/3) sum_r rdi_r[n] * sum_e rdo_r[src_e] * h[src_e, rslice] + bsum
// One wave per node. All 12 ELL loads issued in flight before accumulation
// (predicated, wave-uniform branches) -> MLP 12 instead of 2.
__global__ __launch_bounds__(256) void gather_kernel(
    const ushort* __restrict__ h, const int* __restrict__ deg_in,
    const int* __restrict__ ell, const float* __restrict__ rdi,
    const float* __restrict__ rdo, const float* __restrict__ bsum,
    float* __restrict__ out) {
    int w = threadIdx.x >> 6, l = threadIdx.x & 63;
    int n = blockIdx.x * 4 + w;
    if (n >= N_NODES) return;
    float ox = 0.f, oy = 0.f;
    #pragma unroll
    for (int r = 0; r < 3; ++r) {
        int base = r * N_NODES + n;
        int cnt = min(deg_in[base], ELL_W);
        int e = 0;
        float cl = 0.f;
        if (l < cnt) {
            e = ell[(size_t)base * ELL_W + l];
            cl = rdo[r * N_NODES + e];
        }
        int   s[ELL_W];
        float c[ELL_W];
        #pragma unroll
        for (int i = 0; i < ELL_W; ++i) {
            s[i] = __shfl(e, i);
            c[i] = __shfl(cl, i);
        }
        uint u[ELL_W];
        #pragma unroll
        for (int i = 0; i < ELL_W; ++i) {
            u[i] = 0;
            if (i < cnt)
                u[i] = *(const uint*)(h + (size_t)s[i] * 384 + r * 128 + 2 * l);
        }
        float ax = 0.f, ay = 0.f;
        #pragma unroll
        for (int i = 0; i < ELL_W; ++i) {
            if (i < cnt) {
                __half2 hv = __builtin_bit_cast(__half2, u[i]);
                ax = fmaf(__low2float(hv), c[i], ax);
                ay = fmaf(__high2float(hv), c[i], ay);
            }
        }
        float rv = rdi[base];
        ox = fmaf(ax, rv, ox);
        oy = fmaf(ay, rv, oy);
    }
    float2 bs = *(const float2*)(bsum + 2 * l);
    float2 o;
    o.x = ox * (1.f / 3.f) + bs.x;
    o.y = oy * (1.f / 3.f) + bs.y;
    *(float2*)(out + (size_t)n * 128 + 2 * l) = o;
}

// Rare path: in-degree > ELL_W. Atomic add into out (runs after gather).
__global__ void ovf_kernel(const ushort* __restrict__ h, const float* __restrict__ rdi,
                           const float* __restrict__ rdo,
                           const int* __restrict__ ovf_cnt, const int2* __restrict__ ovf,
                           float* out) {
    int m = min(*ovf_cnt, OVF_CAP);
    int total = m * 64;
    for (int idx = blockIdx.x * blockDim.x + threadIdx.x; idx < total;
         idx += blockDim.x * gridDim.x) {
        int ent = idx >> 6, l = idx & 63;
        int s = ovf[ent].x;
        int packed = ovf[ent].y;
        int t = packed & 0xFFFFF, r = packed >> 20;
        uint u = *(const uint*)(h + (size_t)s * 384 + r * 128 + 2 * l);
        __half2 hv = __builtin_bit_cast(__half2, u);
        float sc = rdo[r * N_NODES + s] * rdi[r * N_NODES + t] * (1.f / 3.f);
        atomicAdd(out + (size_t)t * 128 + 2 * l + 0, __low2float(hv) * sc);
        atomicAdd(out + (size_t)t * 128 + 2 * l + 1, __high2float(hv) * sc);
    }
}

extern "C" void kernel_launch(void* const* d_in, const int* in_sizes, int n_in,
                              void* d_out, int out_size, void* d_ws, size_t ws_size,
                              hipStream_t stream) {
    const float* x     = (const float*)d_in[0];
    const int*   edges = (const int*)d_in[1];   // [R][2][E] int32
    const float* W     = (const float*)d_in[2]; // [R][D][D]
    const float* b     = (const float*)d_in[3]; // [R][D]
    float* out = (float*)d_out;

    char* ws = (char*)d_ws;
    size_t off = 0;
    auto alloc = [&](size_t bytes) -> void* {
        void* p = ws + off;
        off += (bytes + 255) & ~(size_t)255;
        return p;
    };
    int*   gcur_dst = (int*)alloc((size_t)N_RELS * NB * 4);
    int*   gcur_src = (int*)alloc((size_t)N_RELS * NB * 4);
    int*   ovf_cnt  = (int*)alloc(256);
    size_t zero_bytes = off;                    // memset the three above
    float* bsum     = (float*)alloc((size_t)D * 4);
    ushort* Wt      = (ushort*)alloc((size_t)3 * D * D * 2);
    int2*  ovf      = (int2*)alloc((size_t)OVF_CAP * 8);
    int2*  part_dst = (int2*)alloc((size_t)N_RELS * NB * BCAP * 8);   // 13.8 MB
    int*   part_src = (int*)alloc((size_t)N_RELS * NB * BCAP * 4);    //  6.9 MB
    int*   ell      = (int*)alloc((size_t)NTOT * ELL_W * 4);          // 14.4 MB
    int*   deg_in   = (int*)alloc((size_t)NTOT * 4);
    float* rdi      = (float*)alloc((size_t)NTOT * 4);
    float* rdo      = (float*)alloc((size_t)NTOT * 4);
    ushort* h       = (ushort*)alloc((size_t)N_NODES * 3 * D * 2);    // 76.8 MB

    hipMemsetAsync(ws, 0, zero_bytes, stream);
    prep_w_kernel<<<192, 256, 0, stream>>>(W, b, Wt, bsum);
    fused_kernel<<<GEMM_BLKS + PASS1_BLKS, 256, 0, stream>>>(
        x, Wt, edges, h, part_dst, part_src, gcur_dst, gcur_src);
    pass2_kernel<<<dim3(NB, 3), 256, 0, stream>>>(
        part_dst, part_src, gcur_dst, gcur_src, ell, deg_in, rdi, rdo, ovf_cnt, ovf);
    gather_kernel<<<(N_NODES + 3) / 4, 256, 0, stream>>>(
        h, deg_in, ell, rdi, rdo, bsum, out);
    ovf_kernel<<<16, 256, 0, stream>>>(h, rdi, rdo, ovf_cnt, ovf, out);
}